// Round 12
// baseline (1427.281 us; speedup 1.0000x reference)
//
#include <hip/hip_runtime.h>

#define Bb 64
#define Tt 2048
#define Ii 64
#define Hh 128
#define Gg 384   // 3*H
#define Oo 64

typedef _Float16 f16;
typedef _Float16 half8 __attribute__((ext_vector_type(8)));
typedef __fp16 fp16v2 __attribute__((ext_vector_type(2)));   // cvt_pkrtz native type
typedef float f32x4 __attribute__((ext_vector_type(4)));
typedef unsigned int u32;

// ---------------- K2: fully-fused GRU recurrence. 16 blocks x 512 threads;
// 4 batches/block. x-projection FOLDED INTO the step MFMA as a K-extension:
//   pre_r/z = [h|x] @ [W_hr|W_ir]^T (+b)   — additive, fused (6 k-slices)
//   pre_n   = h@W_hn^T + b_hn (accn) and x@W_in^T + b_in (accx) kept separate:
//   n = tanh(accx + r*accn)  [gate algebra: r multiplies only the h-part]
// h-machinery identical to R9 (best measured 934 cy/step): batch b in A-row 4b,
// C row 4b = (hi=b, reg 0) -> every lane evals its own (b=bb0+hi, j=jj) gates;
// A-frag re-read by lanes lo in {0,4,8,12}; ping-pong LDS, 1 syncthreads/step.
// x staged per step by waves 0-1 (512 B: float2 load + cvt_pkrtz + ds_write_b32,
// 2-step register lead) into the x-region of the same ping-pong buffer.
__global__ __launch_bounds__(512, 2) void gru_mfma(
    const float* __restrict__ W_hh, const float* __restrict__ b_hh,
    const float* __restrict__ W_ih, const float* __restrict__ b_ih,
    const float* __restrict__ inputs, float* __restrict__ latents)
{
    __shared__ __align__(16) unsigned char hsm[2][1536];
    // bytes 0..1023: h region [b][j] f16 (R9 layout, b-parity XOR)
    // bytes 1024..1535: x region [b][k] f16, XOR ((b&1)<<6) on k-offset

    const int tid = threadIdx.x;
    const int w   = tid >> 6;
    const int l   = tid & 63;
    const int lo  = l & 15;
    const int hi  = l >> 4;
    const int jj  = w * 16 + lo;      // this lane's hidden column
    const int bb0 = blockIdx.x * 4;   // 4 batches per block

    // B fragments: lane lo -> col jj, hi -> k-chunk of 8.
    // ks 0-3: W_hh k = ks*32+hi*8;  ks 4-5: W_ih k = (ks-4)*32+hi*8.
    half8 Bf[3][6];
#pragma unroll
    for (int gt = 0; gt < 3; ++gt) {
#pragma unroll
        for (int ks = 0; ks < 4; ++ks) {
            const float* wp = W_hh + (size_t)(gt * 128 + jj) * 128 + ks * 32 + hi * 8;
            half8 hv;
#pragma unroll
            for (int q = 0; q < 8; ++q) hv[q] = (f16)wp[q];
            Bf[gt][ks] = hv;
        }
#pragma unroll
        for (int ks = 4; ks < 6; ++ks) {
            const float* wp = W_ih + (size_t)(gt * 128 + jj) * 64 + (ks - 4) * 32 + hi * 8;
            half8 hv;
#pragma unroll
            for (int q = 0; q < 8; ++q) hv[q] = (f16)wp[q];
            Bf[gt][ks] = hv;
        }
    }
#pragma unroll
    for (int gt = 0; gt < 3; ++gt)
#pragma unroll
        for (int ks = 0; ks < 6; ++ks)
            asm volatile("" : "+v"(Bf[gt][ks]));

    const float br  = b_hh[jj]       + b_ih[jj];        // r: fully additive
    const float bz  = b_hh[128 + jj] + b_ih[128 + jj];  // z: fully additive
    const float bnh = b_hh[256 + jj];                   // n h-part (inside r*())
    const float bnx = b_ih[256 + jj];                   // n x-part

    float* latp = latents + (size_t)(bb0 + hi) * Tt * 128 + jj;

    // h-region addresses (R9-validated).
    const int waddr = hi * 256 + ((2 * jj) ^ ((hi & 1) << 6));
    const int rxor  = ((lo >> 2) & 1) << 6;
    const int rb    = (lo << 6);    // h A-read base (b = lo>>2)
    const int xrb   = 1024 + (lo << 5);   // x A-read base (b*128 for lo in 4Z)

    // x staging (tid < 128): thread covers (b = tid>>5, kpair = tid&31).
    const int xb  = (tid >> 5) & 3;
    const int xkp = tid & 31;
    const float* xsrc = inputs + (size_t)(bb0 + xb) * Tt * 64 + 2 * xkp;
    const int xwaddr  = 1024 + xb * 128 + ((4 * xkp) ^ ((xb & 1) << 6));

    // Prologue: stage x(0) into hsm[1]; preload x(1), x(2) into regs.
    u32 xpA = 0, xpB = 0;
    if (tid < 128) {
        const float2 v0 = *(const float2*)(xsrc);
        *(fp16v2*)(&hsm[1][xwaddr]) = __builtin_amdgcn_cvt_pkrtz(v0.x, v0.y);
        const float2 v1 = *(const float2*)(xsrc + 64);
        xpA = __builtin_bit_cast(u32, __builtin_amdgcn_cvt_pkrtz(v1.x, v1.y));
        const float2 v2 = *(const float2*)(xsrc + 128);
        xpB = __builtin_bit_cast(u32, __builtin_amdgcn_cvt_pkrtz(v2.x, v2.y));
    }

    float hreg = 0.f;
    half8 A[4], Ax[2];
    {
        half8 z8 = {};
#pragma unroll
        for (int ks = 0; ks < 4; ++ks) A[ks] = z8;   // h(0) = 0; rows != 4b stay 0
        Ax[0] = z8; Ax[1] = z8;
    }

    __syncthreads();
    if (!(lo & 3)) {   // load x(0) A-fragments
        Ax[0] = *(const half8*)(&hsm[1][xrb + ((hi * 16) ^ rxor)]);
        Ax[1] = *(const half8*)(&hsm[1][xrb + ((64 + hi * 16) ^ rxor)]);
    }

#define GSTEP(T, WP, XP)                                                         \
    {                                                                            \
        const int t_ = (T);                                                      \
        f32x4 accr = {br, br, br, br};                                           \
        f32x4 accz = {bz, bz, bz, bz};                                           \
        f32x4 accn = {bnh, bnh, bnh, bnh};                                       \
        f32x4 accx = {bnx, bnx, bnx, bnx};                                       \
        accr = __builtin_amdgcn_mfma_f32_16x16x32_f16(Ax[0], Bf[0][4], accr, 0, 0, 0); \
        accz = __builtin_amdgcn_mfma_f32_16x16x32_f16(Ax[0], Bf[1][4], accz, 0, 0, 0); \
        accx = __builtin_amdgcn_mfma_f32_16x16x32_f16(Ax[0], Bf[2][4], accx, 0, 0, 0); \
        accr = __builtin_amdgcn_mfma_f32_16x16x32_f16(Ax[1], Bf[0][5], accr, 0, 0, 0); \
        accz = __builtin_amdgcn_mfma_f32_16x16x32_f16(Ax[1], Bf[1][5], accz, 0, 0, 0); \
        accx = __builtin_amdgcn_mfma_f32_16x16x32_f16(Ax[1], Bf[2][5], accx, 0, 0, 0); \
        _Pragma("unroll") for (int ks = 0; ks < 4; ++ks) {                       \
            accr = __builtin_amdgcn_mfma_f32_16x16x32_f16(A[ks], Bf[0][ks], accr, 0, 0, 0); \
            accz = __builtin_amdgcn_mfma_f32_16x16x32_f16(A[ks], Bf[1][ks], accz, 0, 0, 0); \
            accn = __builtin_amdgcn_mfma_f32_16x16x32_f16(A[ks], Bf[2][ks], accn, 0, 0, 0); \
        }                                                                        \
        /* batch bb0+hi row (=4*hi) lives in reg 0 of this lane group */         \
        const float r = __builtin_amdgcn_rcpf(1.f + __expf(-accr[0]));           \
        const float z = __builtin_amdgcn_rcpf(1.f + __expf(-accz[0]));           \
        const float a = accx[0] + r * accn[0];                                   \
        const float n = 1.f - 2.f * __builtin_amdgcn_rcpf(__expf(2.f * a) + 1.f); \
        const float hnew = n + z * (hreg - n);                                   \
        hreg = hnew;                                                             \
        latp[(size_t)t_ * 128] = hnew;                                           \
        const float other = __shfl_xor(hnew, 1);                                 \
        if (!(l & 1)) {                                                          \
            const fp16v2 pkh = __builtin_amdgcn_cvt_pkrtz(hnew, other);          \
            *(fp16v2*)(&hsm[WP][waddr]) = pkh;                                   \
        }                                                                        \
        if (tid < 128) {                                                         \
            if (t_ + 1 < Tt) *(u32*)(&hsm[WP][xwaddr]) = XP;                     \
            if (t_ + 3 < Tt) {                                                   \
                const float2 v = *(const float2*)(xsrc + (size_t)(t_ + 3) * 64); \
                XP = __builtin_bit_cast(u32, __builtin_amdgcn_cvt_pkrtz(v.x, v.y)); \
            }                                                                    \
        }                                                                        \
        __syncthreads();                                                         \
        if (!(lo & 3)) {                                                         \
            _Pragma("unroll") for (int ks = 0; ks < 4; ++ks)                     \
                A[ks] = *(const half8*)(&hsm[WP][rb + ((ks * 64 + hi * 16) ^ rxor)]); \
            Ax[0] = *(const half8*)(&hsm[WP][xrb + ((hi * 16) ^ rxor)]);         \
            Ax[1] = *(const half8*)(&hsm[WP][xrb + ((64 + hi * 16) ^ rxor)]);    \
        }                                                                        \
    }

    for (int t = 0; t < Tt; t += 2) {
        GSTEP(t,     0, xpA)
        GSTEP(t + 1, 1, xpB)
    }
#undef GSTEP
}

// ---------------- K3: out[row,o] = dot(latents[row,:], W_out[o,:]) + b_out[o]
__global__ __launch_bounds__(256, 1) void outproj_kernel(
    const float* __restrict__ latents, const float* __restrict__ W_out,
    const float* __restrict__ b_out, float* __restrict__ out, int rowsPerWave)
{
    const int lane = threadIdx.x & 63;
    const int wave = threadIdx.x >> 6;

    float w[128];
#pragma unroll
    for (int k = 0; k < 128; ++k) w[k] = W_out[(size_t)lane * 128 + k];
#pragma unroll
    for (int k = 0; k < 128; ++k) asm volatile("" : "+v"(w[k]));
    const float bo = b_out[lane];

    const int waveId  = blockIdx.x * 4 + wave;
    const int rowBase = waveId * rowsPerWave;

#pragma unroll 2
    for (int rr = 0; rr < rowsPerWave; ++rr) {
        const int row = rowBase + rr;
        const float4* l4 = (const float4*)(latents + (size_t)row * 128);
        float a0 = bo, a1 = 0.f, a2 = 0.f, a3 = 0.f;
#pragma unroll
        for (int i = 0; i < 32; ++i) {
            float4 v = l4[i];
            a0 = fmaf(v.x, w[4 * i + 0], a0);
            a1 = fmaf(v.y, w[4 * i + 1], a1);
            a2 = fmaf(v.z, w[4 * i + 2], a2);
            a3 = fmaf(v.w, w[4 * i + 3], a3);
        }
        out[(size_t)row * 64 + lane] = (a0 + a1) + (a2 + a3);
    }
}

extern "C" void kernel_launch(void* const* d_in, const int* in_sizes, int n_in,
                              void* d_out, int out_size, void* d_ws, size_t ws_size,
                              hipStream_t stream) {
    const float* inputs = (const float*)d_in[0];
    const float* W_ih   = (const float*)d_in[1];
    const float* W_hh   = (const float*)d_in[2];
    const float* b_ih   = (const float*)d_in[3];
    const float* b_hh   = (const float*)d_in[4];
    const float* W_out  = (const float*)d_in[5];
    const float* b_out  = (const float*)d_in[6];

    float* out     = (float*)d_out;
    float* latents = out + (size_t)Bb * Tt * Oo;

    // No x_proj staging at all anymore: the x-projection is fused into the
    // recurrence kernel as a K-extension MFMA. d_ws unused.
    gru_mfma<<<16, 512, 0, stream>>>(W_hh, b_hh, W_ih, b_ih, inputs, latents);
    outproj_kernel<<<2048, 256, 0, stream>>>(latents, W_out, b_out, out, 16);
}

// Round 13
// 1131.973 us; speedup vs baseline: 1.2609x; 1.2609x over previous
//
#include <hip/hip_runtime.h>

#define Bb 64
#define Tt 2048
#define Ii 64
#define Hh 128
#define Gg 384   // 3*H
#define Oo 64

typedef _Float16 f16;
typedef _Float16 half8 __attribute__((ext_vector_type(8)));
typedef __fp16 fp16v2 __attribute__((ext_vector_type(2)));   // cvt_pkrtz native type
typedef float f32x4 __attribute__((ext_vector_type(4)));
typedef unsigned int u32;

// ---------------- K2: fully-fused GRU recurrence. 16 blocks x 512 threads;
// 4 batches/block. x-projection folded into the step MFMA as a K-extension:
//   pre_r = [h|x]@[W_hr|W_ir]^T + b   (split accumulators: accrH 4-chain + accrX 2-chain)
//   pre_z = likewise
//   n = tanh(accx + r*accn)           (x-part and h-part kept separate)
// Schedule discipline (R9-validated, R12 broke it):
//   - x global load issued at TOP of step, distance-2 (issue->barrier ~1 full
//     step >= L3 latency, so the __syncthreads vmcnt(0) drain is free)
//   - max dependent-MFMA chain = 4 (x-MFMAs first, independent)
// h-machinery identical to R9 (batch b in A-row 4b; C row 4b = (hi=b, reg 0);
// lane (hi,lo) evals its own (b,j); A-frag re-read by lanes lo in {0,4,8,12};
// ping-pong LDS, 1 __syncthreads per step).
__global__ __launch_bounds__(512, 2) void gru_mfma(
    const float* __restrict__ W_hh, const float* __restrict__ b_hh,
    const float* __restrict__ W_ih, const float* __restrict__ b_ih,
    const float* __restrict__ inputs, float* __restrict__ latents)
{
    __shared__ __align__(16) unsigned char hsm[2][1536];
    // bytes 0..1023: h region [b][j] f16 (R9 layout, b-parity XOR)
    // bytes 1024..1535: x region [b][k] f16, XOR ((b&1)<<6) on k-offset

    const int tid = threadIdx.x;
    const int w   = tid >> 6;
    const int l   = tid & 63;
    const int lo  = l & 15;
    const int hi  = l >> 4;
    const int jj  = w * 16 + lo;      // this lane's hidden column
    const int bb0 = blockIdx.x * 4;   // 4 batches per block

    // B fragments: lane lo -> col jj, hi -> k-chunk of 8.
    // ks 0-3: W_hh k = ks*32+hi*8;  ks 4-5: W_ih k = (ks-4)*32+hi*8.
    half8 Bf[3][6];
#pragma unroll
    for (int gt = 0; gt < 3; ++gt) {
#pragma unroll
        for (int ks = 0; ks < 4; ++ks) {
            const float* wp = W_hh + (size_t)(gt * 128 + jj) * 128 + ks * 32 + hi * 8;
            half8 hv;
#pragma unroll
            for (int q = 0; q < 8; ++q) hv[q] = (f16)wp[q];
            Bf[gt][ks] = hv;
        }
#pragma unroll
        for (int ks = 4; ks < 6; ++ks) {
            const float* wp = W_ih + (size_t)(gt * 128 + jj) * 64 + (ks - 4) * 32 + hi * 8;
            half8 hv;
#pragma unroll
            for (int q = 0; q < 8; ++q) hv[q] = (f16)wp[q];
            Bf[gt][ks] = hv;
        }
    }
#pragma unroll
    for (int gt = 0; gt < 3; ++gt)
#pragma unroll
        for (int ks = 0; ks < 6; ++ks)
            asm volatile("" : "+v"(Bf[gt][ks]));

    const float br  = b_hh[jj]       + b_ih[jj];        // r: fully additive
    const float bz  = b_hh[128 + jj] + b_ih[128 + jj];  // z: fully additive
    const float bnh = b_hh[256 + jj];                   // n h-part (inside r*())
    const float bnx = b_ih[256 + jj];                   // n x-part

    float* latp = latents + (size_t)(bb0 + hi) * Tt * 128 + jj;

    // h-region addresses (R9-validated).
    const int waddr = hi * 256 + ((2 * jj) ^ ((hi & 1) << 6));
    const int rxor  = ((lo >> 2) & 1) << 6;
    const int rb    = (lo << 6);          // h A-read base (b = lo>>2)
    const int xrb   = 1024 + (lo << 5);   // x A-read base

    // x staging (tid < 128): thread covers (b = tid>>5, kpair = tid&31).
    const int xb  = (tid >> 5) & 3;
    const int xkp = tid & 31;
    const float* xsrc = inputs + (size_t)(bb0 + xb) * Tt * 64 + 2 * xkp;
    const int xwaddr  = 1024 + xb * 128 + ((4 * xkp) ^ ((xb & 1) << 6));

    // Prologue: stage x(0) into hsm[1]; XW holds packed x(1).
    u32 XW = 0;
    float2 VN = {0.f, 0.f};
    if (tid < 128) {
        const float2 v0 = *(const float2*)(xsrc);
        *(fp16v2*)(&hsm[1][xwaddr]) = __builtin_amdgcn_cvt_pkrtz(v0.x, v0.y);
        const float2 v1 = *(const float2*)(xsrc + 64);
        XW = __builtin_bit_cast(u32, __builtin_amdgcn_cvt_pkrtz(v1.x, v1.y));
    }

    float hreg = 0.f;
    half8 A[4], Ax[2];
    {
        half8 z8 = {};
#pragma unroll
        for (int ks = 0; ks < 4; ++ks) A[ks] = z8;   // h(0) = 0; rows != 4b stay 0
        Ax[0] = z8; Ax[1] = z8;
    }

    __syncthreads();
    if (!(lo & 3)) {   // load x(0) A-fragments
        Ax[0] = *(const half8*)(&hsm[1][xrb + ((hi * 16) ^ rxor)]);
        Ax[1] = *(const half8*)(&hsm[1][xrb + ((64 + hi * 16) ^ rxor)]);
    }

#define GSTEP(T, WP)                                                             \
    {                                                                            \
        const int t_ = (T);                                                      \
        /* TOP: issue x(t+2) load — a full step before this step's barrier */    \
        if (tid < 128 && t_ + 2 < Tt)                                            \
            VN = *(const float2*)(xsrc + (size_t)(t_ + 2) * 64);                 \
        f32x4 accrH = {br, br, br, br};                                          \
        f32x4 acczH = {bz, bz, bz, bz};                                          \
        f32x4 accn  = {bnh, bnh, bnh, bnh};                                      \
        f32x4 accx  = {bnx, bnx, bnx, bnx};                                      \
        f32x4 accrX = {0.f, 0.f, 0.f, 0.f};                                      \
        f32x4 acczX = {0.f, 0.f, 0.f, 0.f};                                      \
        /* x-MFMAs first: operands ready at step start, 2-chain, independent */  \
        accrX = __builtin_amdgcn_mfma_f32_16x16x32_f16(Ax[0], Bf[0][4], accrX, 0, 0, 0); \
        acczX = __builtin_amdgcn_mfma_f32_16x16x32_f16(Ax[0], Bf[1][4], acczX, 0, 0, 0); \
        accx  = __builtin_amdgcn_mfma_f32_16x16x32_f16(Ax[0], Bf[2][4], accx,  0, 0, 0); \
        accrX = __builtin_amdgcn_mfma_f32_16x16x32_f16(Ax[1], Bf[0][5], accrX, 0, 0, 0); \
        acczX = __builtin_amdgcn_mfma_f32_16x16x32_f16(Ax[1], Bf[1][5], acczX, 0, 0, 0); \
        accx  = __builtin_amdgcn_mfma_f32_16x16x32_f16(Ax[1], Bf[2][5], accx,  0, 0, 0); \
        _Pragma("unroll") for (int ks = 0; ks < 4; ++ks) {                       \
            accrH = __builtin_amdgcn_mfma_f32_16x16x32_f16(A[ks], Bf[0][ks], accrH, 0, 0, 0); \
            acczH = __builtin_amdgcn_mfma_f32_16x16x32_f16(A[ks], Bf[1][ks], acczH, 0, 0, 0); \
            accn  = __builtin_amdgcn_mfma_f32_16x16x32_f16(A[ks], Bf[2][ks], accn,  0, 0, 0); \
        }                                                                        \
        /* batch bb0+hi row (=4*hi) lives in reg 0 of this lane group */         \
        const float r = __builtin_amdgcn_rcpf(1.f + __expf(-(accrH[0] + accrX[0]))); \
        const float z = __builtin_amdgcn_rcpf(1.f + __expf(-(acczH[0] + acczX[0]))); \
        const float a = accx[0] + r * accn[0];                                   \
        const float n = 1.f - 2.f * __builtin_amdgcn_rcpf(__expf(2.f * a) + 1.f); \
        const float hnew = n + z * (hreg - n);                                   \
        hreg = hnew;                                                             \
        latp[(size_t)t_ * 128] = hnew;                                           \
        const float other = __shfl_xor(hnew, 1);                                 \
        if (!(l & 1)) {                                                          \
            const fp16v2 pkh = __builtin_amdgcn_cvt_pkrtz(hnew, other);          \
            *(fp16v2*)(&hsm[WP][waddr]) = pkh;                                   \
        }                                                                        \
        if (tid < 128) {                                                         \
            if (t_ + 1 < Tt) *(u32*)(&hsm[WP][xwaddr]) = XW;                     \
            if (t_ + 2 < Tt)                                                     \
                XW = __builtin_bit_cast(u32, __builtin_amdgcn_cvt_pkrtz(VN.x, VN.y)); \
        }                                                                        \
        __syncthreads();                                                         \
        if (!(lo & 3)) {                                                         \
            _Pragma("unroll") for (int ks = 0; ks < 4; ++ks)                     \
                A[ks] = *(const half8*)(&hsm[WP][rb + ((ks * 64 + hi * 16) ^ rxor)]); \
            Ax[0] = *(const half8*)(&hsm[WP][xrb + ((hi * 16) ^ rxor)]);         \
            Ax[1] = *(const half8*)(&hsm[WP][xrb + ((64 + hi * 16) ^ rxor)]);    \
        }                                                                        \
    }

    for (int t = 0; t < Tt; t += 2) {
        GSTEP(t,     0)
        GSTEP(t + 1, 1)
    }
#undef GSTEP
}

// ---------------- K3: out[row,o] = dot(latents[row,:], W_out[o,:]) + b_out[o]
__global__ __launch_bounds__(256, 1) void outproj_kernel(
    const float* __restrict__ latents, const float* __restrict__ W_out,
    const float* __restrict__ b_out, float* __restrict__ out, int rowsPerWave)
{
    const int lane = threadIdx.x & 63;
    const int wave = threadIdx.x >> 6;

    float w[128];
#pragma unroll
    for (int k = 0; k < 128; ++k) w[k] = W_out[(size_t)lane * 128 + k];
#pragma unroll
    for (int k = 0; k < 128; ++k) asm volatile("" : "+v"(w[k]));
    const float bo = b_out[lane];

    const int waveId  = blockIdx.x * 4 + wave;
    const int rowBase = waveId * rowsPerWave;

#pragma unroll 2
    for (int rr = 0; rr < rowsPerWave; ++rr) {
        const int row = rowBase + rr;
        const float4* l4 = (const float4*)(latents + (size_t)row * 128);
        float a0 = bo, a1 = 0.f, a2 = 0.f, a3 = 0.f;
#pragma unroll
        for (int i = 0; i < 32; ++i) {
            float4 v = l4[i];
            a0 = fmaf(v.x, w[4 * i + 0], a0);
            a1 = fmaf(v.y, w[4 * i + 1], a1);
            a2 = fmaf(v.z, w[4 * i + 2], a2);
            a3 = fmaf(v.w, w[4 * i + 3], a3);
        }
        out[(size_t)row * 64 + lane] = (a0 + a1) + (a2 + a3);
    }
}

extern "C" void kernel_launch(void* const* d_in, const int* in_sizes, int n_in,
                              void* d_out, int out_size, void* d_ws, size_t ws_size,
                              hipStream_t stream) {
    const float* inputs = (const float*)d_in[0];
    const float* W_ih   = (const float*)d_in[1];
    const float* W_hh   = (const float*)d_in[2];
    const float* b_ih   = (const float*)d_in[3];
    const float* b_hh   = (const float*)d_in[4];
    const float* W_out  = (const float*)d_in[5];
    const float* b_out  = (const float*)d_in[6];

    float* out     = (float*)d_out;
    float* latents = out + (size_t)Bb * Tt * Oo;

    // x-projection fully fused into the recurrence; d_ws unused.
    gru_mfma<<<16, 512, 0, stream>>>(W_hh, b_hh, W_ih, b_ih, inputs, latents);
    outproj_kernel<<<2048, 256, 0, stream>>>(latents, W_out, b_out, out, 16);
}

// Round 14
// 1040.902 us; speedup vs baseline: 1.3712x; 1.0875x over previous
//
#include <hip/hip_runtime.h>

#define Bb 64
#define Tt 2048
#define Ii 64
#define Hh 128
#define Gg 384   // 3*H
#define Oo 64

typedef _Float16 f16;
typedef _Float16 half8 __attribute__((ext_vector_type(8)));
typedef __fp16 fp16v2 __attribute__((ext_vector_type(2)));   // cvt_pkrtz native type
typedef float f32x4 __attribute__((ext_vector_type(4)));
typedef unsigned int u32;

// ---------------- Fully-fused GRU: x-proj + recurrence + out-proj in ONE kernel.
// 16 blocks x 512 threads; 4 batches/block; batch b in A-row 4b (C row 4b =
// (hi=b, reg 0) -> lane (hi,lo) owns (b=bb0+hi, j=jj) for gates).
//   gates:  pre_r/z = [h|x]@[W_h.|W_i.]^T + b  (chains split 2+2 for latency)
//           n = tanh(accx + r*accn)            (x-part separate: r scales h-part only)
//   out:    at step t, A[ks] = latents[t-1] in A-frag layout -> 4 MFMAs on
//           waves 0-3 (B = W_out frags) give out[t-1][b][jj] in reg 0.
// Global-store discipline: latents[t-1] and out[t-1] stored at TOP of step t
// (issue->barrier ~1 full step, so the __syncthreads vmcnt(0) drain no longer
// waits on store-acks). x load also issued at top, distance-2 (R13-validated).
__global__ __launch_bounds__(512, 2) void gru_mfma(
    const float* __restrict__ W_hh, const float* __restrict__ b_hh,
    const float* __restrict__ W_ih, const float* __restrict__ b_ih,
    const float* __restrict__ W_out, const float* __restrict__ b_out,
    const float* __restrict__ inputs, float* __restrict__ out,
    float* __restrict__ latents)
{
    __shared__ __align__(16) unsigned char hsm[2][1536];
    // bytes 0..1023: h region [b][j] f16 (b-parity XOR); 1024..1535: x region

    const int tid = threadIdx.x;
    const int w   = tid >> 6;
    const int l   = tid & 63;
    const int lo  = l & 15;
    const int hi  = l >> 4;
    const int jj  = w * 16 + lo;      // this lane's hidden column
    const int bb0 = blockIdx.x * 4;   // 4 batches per block

    // Gate B fragments: lane lo -> col jj, hi -> k-chunk of 8.
    half8 Bf[3][6];
#pragma unroll
    for (int gt = 0; gt < 3; ++gt) {
#pragma unroll
        for (int ks = 0; ks < 4; ++ks) {
            const float* wp = W_hh + (size_t)(gt * 128 + jj) * 128 + ks * 32 + hi * 8;
            half8 hv;
#pragma unroll
            for (int q = 0; q < 8; ++q) hv[q] = (f16)wp[q];
            Bf[gt][ks] = hv;
        }
#pragma unroll
        for (int ks = 4; ks < 6; ++ks) {
            const float* wp = W_ih + (size_t)(gt * 128 + jj) * 64 + (ks - 4) * 32 + hi * 8;
            half8 hv;
#pragma unroll
            for (int q = 0; q < 8; ++q) hv[q] = (f16)wp[q];
            Bf[gt][ks] = hv;
        }
    }
#pragma unroll
    for (int gt = 0; gt < 3; ++gt)
#pragma unroll
        for (int ks = 0; ks < 6; ++ks)
            asm volatile("" : "+v"(Bf[gt][ks]));

    // Out-proj B fragments (waves 0-3 only): col = jj (<64), k-chunk = hi*8.
    half8 Bw[4];
    float bo = 0.f;
    if (w < 4) {
#pragma unroll
        for (int ks = 0; ks < 4; ++ks) {
            const float* wp = W_out + (size_t)jj * 128 + ks * 32 + hi * 8;
            half8 hv;
#pragma unroll
            for (int q = 0; q < 8; ++q) hv[q] = (f16)wp[q];
            Bw[ks] = hv;
        }
#pragma unroll
        for (int ks = 0; ks < 4; ++ks) asm volatile("" : "+v"(Bw[ks]));
        bo = b_out[jj];
    } else {
        half8 z8 = {};
#pragma unroll
        for (int ks = 0; ks < 4; ++ks) Bw[ks] = z8;
    }

    const float br  = b_hh[jj]       + b_ih[jj];        // r: fully additive
    const float bz  = b_hh[128 + jj] + b_ih[128 + jj];  // z: fully additive
    const float bnh = b_hh[256 + jj];                   // n h-part (inside r*())
    const float bnx = b_ih[256 + jj];                   // n x-part

    float* latp = latents + (size_t)(bb0 + hi) * Tt * 128 + jj;
    float* outp = out     + (size_t)(bb0 + hi) * Tt * 64  + jj;   // w<4 only

    // h-region addresses (R9-validated).
    const int waddr = hi * 256 + ((2 * jj) ^ ((hi & 1) << 6));
    const int rxor  = ((lo >> 2) & 1) << 6;
    const int rb    = (lo << 6);          // h A-read base (b = lo>>2)
    const int xrb   = 1024 + (lo << 5);   // x A-read base

    // x staging (tid < 128): thread covers (b = tid>>5, kpair = tid&31).
    const int xb  = (tid >> 5) & 3;
    const int xkp = tid & 31;
    const float* xsrc = inputs + (size_t)(bb0 + xb) * Tt * 64 + 2 * xkp;
    const int xwaddr  = 1024 + xb * 128 + ((4 * xkp) ^ ((xb & 1) << 6));

    // Prologue: stage x(0) into hsm[1]; XW holds packed x(1).
    u32 XW = 0;
    float2 VN = {0.f, 0.f};
    if (tid < 128) {
        const float2 v0 = *(const float2*)(xsrc);
        *(fp16v2*)(&hsm[1][xwaddr]) = __builtin_amdgcn_cvt_pkrtz(v0.x, v0.y);
        const float2 v1 = *(const float2*)(xsrc + 64);
        XW = __builtin_bit_cast(u32, __builtin_amdgcn_cvt_pkrtz(v1.x, v1.y));
    }

    float hreg = 0.f, hprev = 0.f;
    half8 A[4], Ax[2];
    {
        half8 z8 = {};
#pragma unroll
        for (int ks = 0; ks < 4; ++ks) A[ks] = z8;   // h(0) = 0; rows != 4b stay 0
        Ax[0] = z8; Ax[1] = z8;
    }

    __syncthreads();
    if (!(lo & 3)) {   // load x(0) A-fragments
        Ax[0] = *(const half8*)(&hsm[1][xrb + ((hi * 16) ^ rxor)]);
        Ax[1] = *(const half8*)(&hsm[1][xrb + ((64 + hi * 16) ^ rxor)]);
    }

// Out-proj for the row currently held in A[ks] (= latents[TR]); waves 0-3.
#define OUTSTEP(TR)                                                              \
    if (w < 4) {                                                                 \
        f32x4 aco0 = {bo, bo, bo, bo};                                           \
        f32x4 aco1 = {0.f, 0.f, 0.f, 0.f};                                       \
        aco0 = __builtin_amdgcn_mfma_f32_16x16x32_f16(A[0], Bw[0], aco0, 0, 0, 0); \
        aco1 = __builtin_amdgcn_mfma_f32_16x16x32_f16(A[1], Bw[1], aco1, 0, 0, 0); \
        aco0 = __builtin_amdgcn_mfma_f32_16x16x32_f16(A[2], Bw[2], aco0, 0, 0, 0); \
        aco1 = __builtin_amdgcn_mfma_f32_16x16x32_f16(A[3], Bw[3], aco1, 0, 0, 0); \
        outp[(size_t)(TR) * 64] = aco0[0] + aco1[0];                             \
    }

#define GSTEP(T, WP)                                                             \
    {                                                                            \
        const int t_ = (T);                                                      \
        /* TOP: issue next x load — a full step before this step's barrier */    \
        if (tid < 128 && t_ + 2 < Tt)                                            \
            VN = *(const float2*)(xsrc + (size_t)(t_ + 2) * 64);                 \
        /* gate MFMAs first (critical path); 2-deep chains */                    \
        f32x4 accr0 = {br, br, br, br},    accr1 = {0.f, 0.f, 0.f, 0.f};         \
        f32x4 accz0 = {bz, bz, bz, bz},    accz1 = {0.f, 0.f, 0.f, 0.f};         \
        f32x4 accn0 = {bnh, bnh, bnh, bnh}, accn1 = {0.f, 0.f, 0.f, 0.f};        \
        f32x4 accx  = {bnx, bnx, bnx, bnx};                                      \
        f32x4 accrX = {0.f, 0.f, 0.f, 0.f}, acczX = {0.f, 0.f, 0.f, 0.f};        \
        accrX = __builtin_amdgcn_mfma_f32_16x16x32_f16(Ax[0], Bf[0][4], accrX, 0, 0, 0); \
        acczX = __builtin_amdgcn_mfma_f32_16x16x32_f16(Ax[0], Bf[1][4], acczX, 0, 0, 0); \
        accx  = __builtin_amdgcn_mfma_f32_16x16x32_f16(Ax[0], Bf[2][4], accx,  0, 0, 0); \
        accrX = __builtin_amdgcn_mfma_f32_16x16x32_f16(Ax[1], Bf[0][5], accrX, 0, 0, 0); \
        acczX = __builtin_amdgcn_mfma_f32_16x16x32_f16(Ax[1], Bf[1][5], acczX, 0, 0, 0); \
        accx  = __builtin_amdgcn_mfma_f32_16x16x32_f16(Ax[1], Bf[2][5], accx,  0, 0, 0); \
        accr0 = __builtin_amdgcn_mfma_f32_16x16x32_f16(A[0], Bf[0][0], accr0, 0, 0, 0); \
        accz0 = __builtin_amdgcn_mfma_f32_16x16x32_f16(A[0], Bf[1][0], accz0, 0, 0, 0); \
        accn0 = __builtin_amdgcn_mfma_f32_16x16x32_f16(A[0], Bf[2][0], accn0, 0, 0, 0); \
        accr1 = __builtin_amdgcn_mfma_f32_16x16x32_f16(A[1], Bf[0][1], accr1, 0, 0, 0); \
        accz1 = __builtin_amdgcn_mfma_f32_16x16x32_f16(A[1], Bf[1][1], accz1, 0, 0, 0); \
        accn1 = __builtin_amdgcn_mfma_f32_16x16x32_f16(A[1], Bf[2][1], accn1, 0, 0, 0); \
        accr0 = __builtin_amdgcn_mfma_f32_16x16x32_f16(A[2], Bf[0][2], accr0, 0, 0, 0); \
        accz0 = __builtin_amdgcn_mfma_f32_16x16x32_f16(A[2], Bf[1][2], accz0, 0, 0, 0); \
        accn0 = __builtin_amdgcn_mfma_f32_16x16x32_f16(A[2], Bf[2][2], accn0, 0, 0, 0); \
        accr1 = __builtin_amdgcn_mfma_f32_16x16x32_f16(A[3], Bf[0][3], accr1, 0, 0, 0); \
        accz1 = __builtin_amdgcn_mfma_f32_16x16x32_f16(A[3], Bf[1][3], accz1, 0, 0, 0); \
        accn1 = __builtin_amdgcn_mfma_f32_16x16x32_f16(A[3], Bf[2][3], accn1, 0, 0, 0); \
        /* while gate MFMAs are in flight: prev-row stores (far from barrier) */ \
        if (t_ > 0) {                                                            \
            latp[(size_t)(t_ - 1) * 128] = hprev;                                \
            OUTSTEP(t_ - 1)                                                      \
        }                                                                        \
        /* gate eval: batch bb0+hi row (=4*hi) lives in reg 0 */                 \
        const float pr = accr0[0] + accr1[0] + accrX[0];                         \
        const float pz = accz0[0] + accz1[0] + acczX[0];                         \
        const float pn = accn0[0] + accn1[0];                                    \
        const float r = __builtin_amdgcn_rcpf(1.f + __expf(-pr));                \
        const float z = __builtin_amdgcn_rcpf(1.f + __expf(-pz));                \
        const float a = accx[0] + r * pn;                                        \
        const float n = 1.f - 2.f * __builtin_amdgcn_rcpf(__expf(2.f * a) + 1.f); \
        const float hnew = n + z * (hreg - n);                                   \
        hreg = hnew;                                                             \
        hprev = hnew;                                                            \
        const float other = __shfl_xor(hnew, 1);                                 \
        if (!(l & 1)) {                                                          \
            const fp16v2 pkh = __builtin_amdgcn_cvt_pkrtz(hnew, other);          \
            *(fp16v2*)(&hsm[WP][waddr]) = pkh;                                   \
        }                                                                        \
        if (tid < 128) {                                                         \
            if (t_ + 1 < Tt) *(u32*)(&hsm[WP][xwaddr]) = XW;                     \
            if (t_ + 2 < Tt)                                                     \
                XW = __builtin_bit_cast(u32, __builtin_amdgcn_cvt_pkrtz(VN.x, VN.y)); \
        }                                                                        \
        __syncthreads();                                                         \
        if (!(lo & 3)) {                                                         \
            _Pragma("unroll") for (int ks = 0; ks < 4; ++ks)                     \
                A[ks] = *(const half8*)(&hsm[WP][rb + ((ks * 64 + hi * 16) ^ rxor)]); \
            Ax[0] = *(const half8*)(&hsm[WP][xrb + ((hi * 16) ^ rxor)]);         \
            Ax[1] = *(const half8*)(&hsm[WP][xrb + ((64 + hi * 16) ^ rxor)]);    \
        }                                                                        \
    }

    for (int t = 0; t < Tt; t += 2) {
        GSTEP(t,     0)
        GSTEP(t + 1, 1)
    }

    // Epilogue: final row T-1 (A[ks] holds latents[T-1] after the last barrier).
    latp[(size_t)(Tt - 1) * 128] = hprev;
    OUTSTEP(Tt - 1)
#undef GSTEP
#undef OUTSTEP
}

extern "C" void kernel_launch(void* const* d_in, const int* in_sizes, int n_in,
                              void* d_out, int out_size, void* d_ws, size_t ws_size,
                              hipStream_t stream) {
    const float* inputs = (const float*)d_in[0];
    const float* W_ih   = (const float*)d_in[1];
    const float* W_hh   = (const float*)d_in[2];
    const float* b_ih   = (const float*)d_in[3];
    const float* b_hh   = (const float*)d_in[4];
    const float* W_out  = (const float*)d_in[5];
    const float* b_out  = (const float*)d_in[6];

    float* out     = (float*)d_out;
    float* latents = out + (size_t)Bb * Tt * Oo;

    // Everything fused into one kernel; d_ws unused.
    gru_mfma<<<16, 512, 0, stream>>>(W_hh, b_hh, W_ih, b_ih, W_out, b_out,
                                     inputs, out, latents);
}